// Round 1
// baseline (406.334 us; speedup 1.0000x reference)
//
#include <hip/hip_runtime.h>

typedef unsigned short ushort_t;
typedef __attribute__((ext_vector_type(8))) short bf16x8;
typedef __attribute__((ext_vector_type(4))) float f32x4;

#define DI static __device__ __forceinline__

DI ushort_t f2bf(float f){
  unsigned u = __builtin_bit_cast(unsigned, f);
  u += 0x7fffu + ((u >> 16) & 1u);
  return (ushort_t)(u >> 16);
}
DI float bf2f(ushort_t h){ unsigned u = ((unsigned)h) << 16; return __builtin_bit_cast(float, u); }

DI void gload_lds16(const void* g, void* l){
  __builtin_amdgcn_global_load_lds((const __attribute__((address_space(1))) void*)g,
                                   (__attribute__((address_space(3))) void*)l, 16, 0, 0);
}

// ---------------- prep kernels ----------------

__global__ void cast4_kernel(const float* __restrict__ in, ushort_t* __restrict__ out, int n4){
  int i = blockIdx.x * blockDim.x + threadIdx.x;
  if (i >= n4) return;
  float4 v = ((const float4*)in)[i];
  ushort_t r0 = f2bf(v.x), r1 = f2bf(v.y), r2 = f2bf(v.z), r3 = f2bf(v.w);
  ushort_t* o = out + (size_t)i * 4;
  o[0] = r0; o[1] = r1; o[2] = r2; o[3] = r3;
}

// out[c][r] = in[r][c], per z-block, fp32 -> bf16
__global__ void transpose_cast(const float* __restrict__ in, ushort_t* __restrict__ out,
                               int R, int C, long long in_blk, long long out_blk){
  __shared__ float tile[32][33];
  const float* src = in + (size_t)blockIdx.z * in_blk;
  ushort_t* dst = out + (size_t)blockIdx.z * out_blk;
  int c0 = blockIdx.x * 32, r0 = blockIdx.y * 32;
  int tx = threadIdx.x & 31, ty = threadIdx.x >> 5;  // ty 0..7
  #pragma unroll
  for (int p = 0; p < 4; ++p)
    tile[ty + p * 8][tx] = src[(size_t)(r0 + ty + p * 8) * C + c0 + tx];
  __syncthreads();
  #pragma unroll
  for (int p = 0; p < 4; ++p){
    int rr = ty + p * 8;
    dst[(size_t)(c0 + rr) * R + r0 + tx] = f2bf(tile[tx][rr]);
  }
}

__global__ void build_bqkv(const float* __restrict__ bq, const float* __restrict__ bk,
                           const float* __restrict__ bv, float* __restrict__ bqkv){
  int i = blockIdx.x * 256 + threadIdx.x;
  if (i >= 3 * 1536) return;
  int l = i / 1536, j = i % 1536;
  float v = (j < 512) ? bq[l * 512 + j] : (j < 1024 ? bk[l * 512 + j - 512] : bv[l * 512 + j - 1024]);
  bqkv[i] = v;
}

// ---------------- GEMM: C = A(bf16,[M,K]) * Bt(bf16,[N,K])^T + bias ----------------
// 128x128 tile, BK=64, 4 waves (2x2), m97 structure.

template<int BF16OUT>
__global__ __launch_bounds__(256)
void gemm_bt(const ushort_t* __restrict__ A, const ushort_t* __restrict__ Bt,
             const float* __restrict__ bias, void* __restrict__ Cv,
             int M, int N, int K, int lda, int ldb, int ldc,
             long long sA, long long sB, long long sC, long long sBias){
  __shared__ ushort_t As[128 * 64];
  __shared__ ushort_t Bs[128 * 64];
  const int z = blockIdx.z;
  A += (size_t)z * sA; Bt += (size_t)z * sB; bias += (size_t)z * sBias;
  const int n0 = blockIdx.x * 128, m0 = blockIdx.y * 128;
  const int tid = threadIdx.x, wid = tid >> 6, lane = tid & 63;
  const int wr = wid >> 1, wc = wid & 1, lr = lane & 15, lk = lane >> 4;

  f32x4 acc[4][4] = {};

  for (int k0 = 0; k0 < K; k0 += 64){
    #pragma unroll
    for (int i = 0; i < 4; ++i){
      const int chunk = i * 256 + wid * 64 + lane;
      const int row = chunk >> 3, cc = chunk & 7;
      gload_lds16(A + (size_t)(m0 + row) * lda + (k0 + cc * 8), &As[(i * 256 + wid * 64) * 8]);
      gload_lds16(Bt + (size_t)(n0 + row) * ldb + (k0 + cc * 8), &Bs[(i * 256 + wid * 64) * 8]);
    }
    __syncthreads();
    bf16x8 af[4][2], bfr[4][2];
    #pragma unroll
    for (int m = 0; m < 4; ++m){
      af[m][0] = *(const bf16x8*)&As[(wr * 64 + m * 16 + lr) * 64 + lk * 8];
      af[m][1] = *(const bf16x8*)&As[(wr * 64 + m * 16 + lr) * 64 + 32 + lk * 8];
    }
    #pragma unroll
    for (int n = 0; n < 4; ++n){
      bfr[n][0] = *(const bf16x8*)&Bs[(wc * 64 + n * 16 + lr) * 64 + lk * 8];
      bfr[n][1] = *(const bf16x8*)&Bs[(wc * 64 + n * 16 + lr) * 64 + 32 + lk * 8];
    }
    #pragma unroll
    for (int m = 0; m < 4; ++m)
      #pragma unroll
      for (int n = 0; n < 4; ++n){
        acc[m][n] = __builtin_amdgcn_mfma_f32_16x16x32_bf16(af[m][0], bfr[n][0], acc[m][n], 0, 0, 0);
        acc[m][n] = __builtin_amdgcn_mfma_f32_16x16x32_bf16(af[m][1], bfr[n][1], acc[m][n], 0, 0, 0);
      }
    __syncthreads();
  }

  #pragma unroll
  for (int n = 0; n < 4; ++n){
    const int col = n0 + wc * 64 + n * 16 + lr;
    const float bv = bias[col];
    #pragma unroll
    for (int m = 0; m < 4; ++m){
      const int row0 = m0 + wr * 64 + m * 16 + lk * 4;
      #pragma unroll
      for (int j = 0; j < 4; ++j){
        const float v = acc[m][n][j] + bv;
        const size_t idx = (size_t)z * sC + (size_t)(row0 + j) * ldc + col;
        if (BF16OUT) ((ushort_t*)Cv)[idx] = f2bf(v);
        else         ((float*)Cv)[idx] = v;
      }
    }
  }
}

// ---------------- LayerNorm: xl fp32 [4096,1536] -> xn bf16, rows of 512 per (l,bs) ----------------

__global__ __launch_bounds__(256)
void ln_kernel(const float* __restrict__ xl, ushort_t* __restrict__ xn,
               const float* __restrict__ gamma, const float* __restrict__ beta){
  int rid = blockIdx.x * 4 + (threadIdx.x >> 6);
  int lane = threadIdx.x & 63;
  int l = rid >> 12, bs = rid & 4095;
  const float* row = xl + (size_t)bs * 1536 + l * 512;
  ushort_t* orow = xn + (size_t)bs * 1536 + l * 512;
  float4 a = ((const float4*)row)[lane * 2];
  float4 b4 = ((const float4*)row)[lane * 2 + 1];
  float vals[8] = {a.x, a.y, a.z, a.w, b4.x, b4.y, b4.z, b4.w};
  float s = 0.f, ss = 0.f;
  #pragma unroll
  for (int j = 0; j < 8; ++j){ s += vals[j]; ss += vals[j] * vals[j]; }
  #pragma unroll
  for (int off = 32; off; off >>= 1){
    s += __shfl_xor(s, off);
    ss += __shfl_xor(ss, off);
  }
  float mean = s * (1.0f / 512.0f);
  float var = ss * (1.0f / 512.0f) - mean * mean;
  float inv = rsqrtf(var + 1e-5f);
  const float* g = gamma + l * 512 + lane * 8;
  const float* be = beta + l * 512 + lane * 8;
  float4 g0 = ((const float4*)g)[0], g1 = ((const float4*)g)[1];
  float4 be0 = ((const float4*)be)[0], be1 = ((const float4*)be)[1];
  float gs[8] = {g0.x, g0.y, g0.z, g0.w, g1.x, g1.y, g1.z, g1.w};
  float bs8[8] = {be0.x, be0.y, be0.z, be0.w, be1.x, be1.y, be1.z, be1.w};
  bf16x8 r;
  #pragma unroll
  for (int j = 0; j < 8; ++j)
    r[j] = (short)f2bf((vals[j] - mean) * inv * gs[j] + bs8[j]);
  *(bf16x8*)(orow + lane * 8) = r;
}

// ---------------- Flash attention ----------------
// grid (32 qblocks, 8 heads, 6 = L*B). 256 threads = 4 waves x 16 Q-rows. KV tile = 64.

__global__ __launch_bounds__(256)
void attn_kernel(const ushort_t* __restrict__ qkv, const int* __restrict__ mask,
                 ushort_t* __restrict__ att){
  const int qb = blockIdx.x, h = blockIdx.y, z = blockIdx.z;
  const int l = z >> 1, b = z & 1;
  const int* mrow = mask + b * 2048;
  const size_t base = ((size_t)(l * 4096 + b * 2048)) * 1536;
  const ushort_t* Qb = qkv + base + h * 64;
  const ushort_t* Kb = qkv + base + 512 + h * 64;
  const ushort_t* Vb = qkv + base + 1024 + h * 64;

  __shared__ ushort_t Ks[64 * 64];      // XOR-swizzled content (pre-swizzled global source)
  __shared__ ushort_t Vt[64 * 72];      // V^T, padded stride 72 (conflict-free)
  __shared__ ushort_t Pl[4][16 * 72];   // per-wave P, padded stride 72

  const int tid = threadIdx.x, wid = tid >> 6, lane = tid & 63;
  const int lr = lane & 15, lk = lane >> 4;
  const int qrow = qb * 64 + wid * 16 + lr;

  const ushort_t* qp = Qb + (size_t)qrow * 1536 + lk * 8;
  const bf16x8 q0 = *(const bf16x8*)qp;
  const bf16x8 q1 = *(const bf16x8*)(qp + 32);

  f32x4 o[4] = {};
  float mrun[4] = {-3e38f, -3e38f, -3e38f, -3e38f};
  float lrun[4] = {0.f, 0.f, 0.f, 0.f};

  for (int kt = 0; kt < 32; ++kt){
    const int k0 = kt * 64;
    // stage K (64 rows x 64), source chunk XOR-swizzled so reads are conflict-free
    #pragma unroll
    for (int i = 0; i < 2; ++i){
      const int chunk = i * 256 + wid * 64 + lane;
      const int row = chunk >> 3, cs = chunk & 7;
      const int cc = cs ^ (row & 7);
      gload_lds16(Kb + (size_t)(k0 + row) * 1536 + cc * 8, &Ks[(i * 256 + wid * 64) * 8]);
    }
    // stage V^T (reg-staged, padded LDS)
    #pragma unroll
    for (int p = 0; p < 2; ++p){
      const int idx = p * 256 + tid;
      const int key = idx >> 3, i = idx & 7;
      bf16x8 vv = *(const bf16x8*)(Vb + (size_t)(k0 + key) * 1536 + i * 8);
      #pragma unroll
      for (int j = 0; j < 8; ++j)
        Vt[(i * 8 + j) * 72 + key] = (ushort_t)vv[j];
    }
    __syncthreads();

    // scores: 4 halves of 16 keys each
    float sc[4][4];
    #pragma unroll
    for (int hh = 0; hh < 4; ++hh){
      const int krow = hh * 16 + lr;
      const int sw = lr & 7;
      bf16x8 kf0 = *(const bf16x8*)&Ks[krow * 64 + ((0 + lk) ^ sw) * 8];
      bf16x8 kf1 = *(const bf16x8*)&Ks[krow * 64 + ((4 + lk) ^ sw) * 8];
      f32x4 t = {0.f, 0.f, 0.f, 0.f};
      t = __builtin_amdgcn_mfma_f32_16x16x32_bf16(q0, kf0, t, 0, 0, 0);
      t = __builtin_amdgcn_mfma_f32_16x16x32_bf16(q1, kf1, t, 0, 0, 0);
      const int key = k0 + hh * 16 + lr;
      const bool msk = (mrow[key] == 0);
      #pragma unroll
      for (int j = 0; j < 4; ++j)
        sc[hh][j] = msk ? -1e9f : t[j] * 0.125f;
    }

    // online softmax (per lane: 4 q-rows; reduce over 16 key-lanes)
    float tmax[4], scale[4], psum[4];
    #pragma unroll
    for (int j = 0; j < 4; ++j){
      float m01 = fmaxf(sc[0][j], sc[1][j]);
      float m23 = fmaxf(sc[2][j], sc[3][j]);
      tmax[j] = fmaxf(m01, m23);
    }
    #pragma unroll
    for (int j = 0; j < 4; ++j){
      #pragma unroll
      for (int off = 1; off < 16; off <<= 1)
        tmax[j] = fmaxf(tmax[j], __shfl_xor(tmax[j], off));
      float mn = fmaxf(mrun[j], tmax[j]);
      scale[j] = __expf(mrun[j] - mn);
      mrun[j] = mn;
      psum[j] = 0.f;
    }
    ushort_t pb[4][4];
    #pragma unroll
    for (int hh = 0; hh < 4; ++hh)
      #pragma unroll
      for (int j = 0; j < 4; ++j){
        float p = __expf(sc[hh][j] - mrun[j]);
        psum[j] += p;
        pb[hh][j] = f2bf(p);
      }
    #pragma unroll
    for (int j = 0; j < 4; ++j){
      #pragma unroll
      for (int off = 1; off < 16; off <<= 1)
        psum[j] += __shfl_xor(psum[j], off);
      lrun[j] = lrun[j] * scale[j] + psum[j];
    }
    #pragma unroll
    for (int n = 0; n < 4; ++n)
      #pragma unroll
      for (int j = 0; j < 4; ++j)
        o[n][j] *= scale[j];

    // P -> LDS (bf16), then read back in A-fragment layout
    ushort_t* pw = &Pl[wid][0];
    #pragma unroll
    for (int hh = 0; hh < 4; ++hh)
      #pragma unroll
      for (int j = 0; j < 4; ++j)
        pw[(lk * 4 + j) * 72 + hh * 16 + lr] = pb[hh][j];
    asm volatile("s_waitcnt lgkmcnt(0)" ::: "memory");
    __builtin_amdgcn_sched_barrier(0);
    bf16x8 pf0 = *(const bf16x8*)&pw[lr * 72 + lk * 8];
    bf16x8 pf1 = *(const bf16x8*)&pw[lr * 72 + 32 + lk * 8];

    #pragma unroll
    for (int n = 0; n < 4; ++n){
      bf16x8 v0 = *(const bf16x8*)&Vt[(n * 16 + lr) * 72 + lk * 8];
      bf16x8 v1 = *(const bf16x8*)&Vt[(n * 16 + lr) * 72 + 32 + lk * 8];
      o[n] = __builtin_amdgcn_mfma_f32_16x16x32_bf16(pf0, v0, o[n], 0, 0, 0);
      o[n] = __builtin_amdgcn_mfma_f32_16x16x32_bf16(pf1, v1, o[n], 0, 0, 0);
    }
    __syncthreads();
  }

  float inv[4];
  #pragma unroll
  for (int j = 0; j < 4; ++j) inv[j] = 1.0f / lrun[j];
  const size_t arow0 = (size_t)(b * 2048 + qb * 64 + wid * 16);
  #pragma unroll
  for (int n = 0; n < 4; ++n)
    #pragma unroll
    for (int j = 0; j < 4; ++j)
      att[(arow0 + lk * 4 + j) * 1536 + l * 512 + h * 64 + n * 16 + lr] = f2bf(o[n][j] * inv[j]);
}

// ---------------- launch ----------------

extern "C" void kernel_launch(void* const* d_in, const int* in_sizes, int n_in,
                              void* d_out, int out_size, void* d_ws, size_t ws_size,
                              hipStream_t stream){
  const float* x    = (const float*)d_in[0];
  const int*   mask = (const int*)d_in[1];
  const float* Wp   = (const float*)d_in[2];
  const float* bp   = (const float*)d_in[3];
  const float* gamma= (const float*)d_in[4];
  const float* beta = (const float*)d_in[5];
  const float* Wq   = (const float*)d_in[6];
  const float* bq   = (const float*)d_in[7];
  const float* Wk   = (const float*)d_in[8];
  const float* bk   = (const float*)d_in[9];
  const float* Wv   = (const float*)d_in[10];
  const float* bv   = (const float*)d_in[11];
  const float* Wo   = (const float*)d_in[12];
  const float* bo   = (const float*)d_in[13];
  const float* Wout = (const float*)d_in[14];
  const float* bout = (const float*)d_in[15];

  char* ws = (char*)d_ws;
  size_t off = 0;
  auto alloc = [&](size_t bytes){ void* p = ws + off; off += (bytes + 255) & ~(size_t)255; return p; };
  ushort_t* xb    = (ushort_t*)alloc(4096ull * 512 * 2);
  ushort_t* WpT   = (ushort_t*)alloc(1536ull * 512 * 2);
  ushort_t* WqkvT = (ushort_t*)alloc(3ull * 1536 * 512 * 2);
  ushort_t* WoT   = (ushort_t*)alloc(3ull * 512 * 512 * 2);
  ushort_t* WoutT = (ushort_t*)alloc(512ull * 1536 * 2);
  float*    bqkv  = (float*)alloc(3ull * 1536 * 4);
  float*    xl    = (float*)alloc(4096ull * 1536 * 4);
  ushort_t* xn    = (ushort_t*)alloc(4096ull * 1536 * 2);
  ushort_t* qkv   = (ushort_t*)alloc(3ull * 4096 * 1536 * 2);
  ushort_t* lev   = (ushort_t*)alloc(4096ull * 1536 * 2);
  ushort_t* att   = (ushort_t*)xl;  // alias: xl dead after ln_kernel, attn runs later

  cast4_kernel<<<2048, 256, 0, stream>>>(x, xb, 524288);
  transpose_cast<<<dim3(16, 16, 3), 256, 0, stream>>>(Wp, WpT, 512, 512, 262144, 262144);
  transpose_cast<<<dim3(16, 16, 3), 256, 0, stream>>>(Wq, WqkvT + 0,      512, 512, 262144, 786432);
  transpose_cast<<<dim3(16, 16, 3), 256, 0, stream>>>(Wk, WqkvT + 262144, 512, 512, 262144, 786432);
  transpose_cast<<<dim3(16, 16, 3), 256, 0, stream>>>(Wv, WqkvT + 524288, 512, 512, 262144, 786432);
  transpose_cast<<<dim3(16, 16, 3), 256, 0, stream>>>(Wo, WoT, 512, 512, 262144, 262144);
  transpose_cast<<<dim3(16, 48, 1), 256, 0, stream>>>(Wout, WoutT, 1536, 512, 0, 0);
  build_bqkv<<<18, 256, 0, stream>>>(bq, bk, bv, bqkv);

  // xl = x @ Wp + bp   [4096,1536] fp32
  gemm_bt<0><<<dim3(12, 32, 1), 256, 0, stream>>>(xb, WpT, bp, xl,
      4096, 1536, 512, 512, 512, 1536, 0, 0, 0, 0);
  // LayerNorm -> xn bf16
  ln_kernel<<<3072, 256, 0, stream>>>(xl, xn, gamma, beta);
  // qkv[l] = xn[l] @ Wqkv[l] + bqkv[l]   bf16 [3][4096][1536]
  gemm_bt<1><<<dim3(12, 32, 3), 256, 0, stream>>>(xn, WqkvT, bqkv, qkv,
      4096, 1536, 512, 1536, 512, 1536, 512, 786432, 4096ll * 1536, 1536);
  // flash attention -> att bf16 [4096][1536] (combined-level layout)
  attn_kernel<<<dim3(32, 8, 6), 256, 0, stream>>>(qkv, mask, att);
  // lev[l] = att[l] @ Wo[l] + bo[l]   bf16 [4096][1536]
  gemm_bt<1><<<dim3(4, 32, 3), 256, 0, stream>>>(att, WoT, bo, lev,
      4096, 512, 512, 1536, 512, 1536, 512, 262144, 512, 512);
  // out = lev @ Wout + bout   fp32 [4096][512]
  gemm_bt<0><<<dim3(4, 32, 1), 256, 0, stream>>>(lev, WoutT, bout, (float*)d_out,
      4096, 512, 1536, 1536, 1536, 512, 0, 0, 0, 0);
}

// Round 2
// 274.739 us; speedup vs baseline: 1.4790x; 1.4790x over previous
//
#include <hip/hip_runtime.h>

typedef unsigned short ushort_t;
typedef __attribute__((ext_vector_type(8))) short bf16x8;
typedef __attribute__((ext_vector_type(4))) short short4v;
typedef __attribute__((ext_vector_type(4))) float f32x4;

#define DI static __device__ __forceinline__

DI ushort_t f2bf(float f){
  unsigned u = __builtin_bit_cast(unsigned, f);
  u += 0x7fffu + ((u >> 16) & 1u);
  return (ushort_t)(u >> 16);
}
DI float bf2f(ushort_t h){ unsigned u = ((unsigned)h) << 16; return __builtin_bit_cast(float, u); }

DI void gload_lds16(const void* g, void* l){
  __builtin_amdgcn_global_load_lds((const __attribute__((address_space(1))) void*)g,
                                   (__attribute__((address_space(3))) void*)l, 16, 0, 0);
}

// ---------------- prep kernels ----------------

__global__ void cast4_kernel(const float* __restrict__ in, ushort_t* __restrict__ out, int n4){
  int i = blockIdx.x * blockDim.x + threadIdx.x;
  if (i >= n4) return;
  float4 v = ((const float4*)in)[i];
  ushort_t r0 = f2bf(v.x), r1 = f2bf(v.y), r2 = f2bf(v.z), r3 = f2bf(v.w);
  ushort_t* o = out + (size_t)i * 4;
  o[0] = r0; o[1] = r1; o[2] = r2; o[3] = r3;
}

// out[c][r] = in[r][c], per z-block, fp32 -> bf16
__global__ void transpose_cast(const float* __restrict__ in, ushort_t* __restrict__ out,
                               int R, int C, long long in_blk, long long out_blk){
  __shared__ float tile[32][33];
  const float* src = in + (size_t)blockIdx.z * in_blk;
  ushort_t* dst = out + (size_t)blockIdx.z * out_blk;
  int c0 = blockIdx.x * 32, r0 = blockIdx.y * 32;
  int tx = threadIdx.x & 31, ty = threadIdx.x >> 5;  // ty 0..7
  #pragma unroll
  for (int p = 0; p < 4; ++p)
    tile[ty + p * 8][tx] = src[(size_t)(r0 + ty + p * 8) * C + c0 + tx];
  __syncthreads();
  #pragma unroll
  for (int p = 0; p < 4; ++p){
    int rr = ty + p * 8;
    dst[(size_t)(c0 + rr) * R + r0 + tx] = f2bf(tile[tx][rr]);
  }
}

__global__ void build_bqkv(const float* __restrict__ bq, const float* __restrict__ bk,
                           const float* __restrict__ bv, float* __restrict__ bqkv){
  int i = blockIdx.x * 256 + threadIdx.x;
  if (i >= 3 * 1536) return;
  int l = i / 1536, j = i % 1536;
  float v = (j < 512) ? bq[l * 512 + j] : (j < 1024 ? bk[l * 512 + j - 512] : bv[l * 512 + j - 1024]);
  bqkv[i] = v;
}

// V^T: qkv V-section [l][b*2048+s][1024 + h*64 + d] -> VtG[((l*2+b)*8+h)*64 + d][2048 s]
__global__ __launch_bounds__(256)
void vtrans_kernel(const ushort_t* __restrict__ qkv, ushort_t* __restrict__ VtG){
  __shared__ ushort_t t[64][72];
  const int st = blockIdx.x, h = blockIdx.y, z = blockIdx.z;
  const int l = z >> 1, b = z & 1;
  const ushort_t* src = qkv + ((size_t)l * 4096 + b * 2048 + st * 64) * 1536 + 1024 + h * 64;
  const int r = threadIdx.x >> 2, c4 = threadIdx.x & 3;
  bf16x8 v0 = *(const bf16x8*)(src + (size_t)r * 1536 + c4 * 16);
  bf16x8 v1 = *(const bf16x8*)(src + (size_t)r * 1536 + c4 * 16 + 8);
  #pragma unroll
  for (int j = 0; j < 8; ++j){ t[r][c4 * 16 + j] = (ushort_t)v0[j]; t[r][c4 * 16 + 8 + j] = (ushort_t)v1[j]; }
  __syncthreads();
  bf16x8 o0, o1;
  #pragma unroll
  for (int j = 0; j < 8; ++j){ o0[j] = (short)t[c4 * 16 + j][r]; o1[j] = (short)t[c4 * 16 + 8 + j][r]; }
  ushort_t* dst = VtG + ((size_t)(z * 8 + h) * 64 + r) * 2048 + st * 64 + c4 * 16;
  *(bf16x8*)dst = o0;
  *(bf16x8*)(dst + 8) = o1;
}

// ---------------- GEMM: C = A(bf16,[M,K]) * Bt(bf16,[N,K])^T + bias ----------------

template<int BF16OUT>
__global__ __launch_bounds__(256)
void gemm_bt(const ushort_t* __restrict__ A, const ushort_t* __restrict__ Bt,
             const float* __restrict__ bias, void* __restrict__ Cv,
             int M, int N, int K, int lda, int ldb, int ldc,
             long long sA, long long sB, long long sC, long long sBias){
  __shared__ ushort_t As[128 * 64];
  __shared__ ushort_t Bs[128 * 64];
  const int z = blockIdx.z;
  A += (size_t)z * sA; Bt += (size_t)z * sB; bias += (size_t)z * sBias;
  const int n0 = blockIdx.x * 128, m0 = blockIdx.y * 128;
  const int tid = threadIdx.x, wid = tid >> 6, lane = tid & 63;
  const int wr = wid >> 1, wc = wid & 1, lr = lane & 15, lk = lane >> 4;

  f32x4 acc[4][4] = {};

  for (int k0 = 0; k0 < K; k0 += 64){
    #pragma unroll
    for (int i = 0; i < 4; ++i){
      const int chunk = i * 256 + wid * 64 + lane;
      const int row = chunk >> 3, cc = chunk & 7;
      gload_lds16(A + (size_t)(m0 + row) * lda + (k0 + cc * 8), &As[(i * 256 + wid * 64) * 8]);
      gload_lds16(Bt + (size_t)(n0 + row) * ldb + (k0 + cc * 8), &Bs[(i * 256 + wid * 64) * 8]);
    }
    __syncthreads();
    bf16x8 af[4][2], bfr[4][2];
    #pragma unroll
    for (int m = 0; m < 4; ++m){
      af[m][0] = *(const bf16x8*)&As[(wr * 64 + m * 16 + lr) * 64 + lk * 8];
      af[m][1] = *(const bf16x8*)&As[(wr * 64 + m * 16 + lr) * 64 + 32 + lk * 8];
    }
    #pragma unroll
    for (int n = 0; n < 4; ++n){
      bfr[n][0] = *(const bf16x8*)&Bs[(wc * 64 + n * 16 + lr) * 64 + lk * 8];
      bfr[n][1] = *(const bf16x8*)&Bs[(wc * 64 + n * 16 + lr) * 64 + 32 + lk * 8];
    }
    #pragma unroll
    for (int m = 0; m < 4; ++m)
      #pragma unroll
      for (int n = 0; n < 4; ++n){
        acc[m][n] = __builtin_amdgcn_mfma_f32_16x16x32_bf16(af[m][0], bfr[n][0], acc[m][n], 0, 0, 0);
        acc[m][n] = __builtin_amdgcn_mfma_f32_16x16x32_bf16(af[m][1], bfr[n][1], acc[m][n], 0, 0, 0);
      }
    __syncthreads();
  }

  #pragma unroll
  for (int n = 0; n < 4; ++n){
    const int col = n0 + wc * 64 + n * 16 + lr;
    const float bv = bias[col];
    #pragma unroll
    for (int m = 0; m < 4; ++m){
      const int row0 = m0 + wr * 64 + m * 16 + lk * 4;
      #pragma unroll
      for (int j = 0; j < 4; ++j){
        const float v = acc[m][n][j] + bv;
        const size_t idx = (size_t)z * sC + (size_t)(row0 + j) * ldc + col;
        if (BF16OUT) ((ushort_t*)Cv)[idx] = f2bf(v);
        else         ((float*)Cv)[idx] = v;
      }
    }
  }
}

// ---------------- LayerNorm ----------------

__global__ __launch_bounds__(256)
void ln_kernel(const float* __restrict__ xl, ushort_t* __restrict__ xn,
               const float* __restrict__ gamma, const float* __restrict__ beta){
  int rid = blockIdx.x * 4 + (threadIdx.x >> 6);
  int lane = threadIdx.x & 63;
  int l = rid >> 12, bs = rid & 4095;
  const float* row = xl + (size_t)bs * 1536 + l * 512;
  ushort_t* orow = xn + (size_t)bs * 1536 + l * 512;
  float4 a = ((const float4*)row)[lane * 2];
  float4 b4 = ((const float4*)row)[lane * 2 + 1];
  float vals[8] = {a.x, a.y, a.z, a.w, b4.x, b4.y, b4.z, b4.w};
  float s = 0.f, ss = 0.f;
  #pragma unroll
  for (int j = 0; j < 8; ++j){ s += vals[j]; ss += vals[j] * vals[j]; }
  #pragma unroll
  for (int off = 32; off; off >>= 1){
    s += __shfl_xor(s, off);
    ss += __shfl_xor(ss, off);
  }
  float mean = s * (1.0f / 512.0f);
  float var = ss * (1.0f / 512.0f) - mean * mean;
  float inv = rsqrtf(var + 1e-5f);
  const float* g = gamma + l * 512 + lane * 8;
  const float* be = beta + l * 512 + lane * 8;
  float4 g0 = ((const float4*)g)[0], g1 = ((const float4*)g)[1];
  float4 be0 = ((const float4*)be)[0], be1 = ((const float4*)be)[1];
  float gs[8] = {g0.x, g0.y, g0.z, g0.w, g1.x, g1.y, g1.z, g1.w};
  float bs8[8] = {be0.x, be0.y, be0.z, be0.w, be1.x, be1.y, be1.z, be1.w};
  bf16x8 r;
  #pragma unroll
  for (int j = 0; j < 8; ++j)
    r[j] = (short)f2bf((vals[j] - mean) * inv * gs[j] + bs8[j]);
  *(bf16x8*)(orow + lane * 8) = r;
}

// ---------------- Flash attention (swapped QK^T) ----------------
// grid (32 qblocks, 8 heads, 6 = L*B). 256 threads = 4 waves x 16 Q-rows. KV tile = 64.
// S^T = mfma(K_frag, Q_frag): lane (lr,lk) holds S[k = hh*16+lk*4+j][q = lr].
// Softmax state (mrun,lrun) is scalar per lane (its q = lr), replicated across lk.
// PV: O[q][d] via A=P[q][k] (LDS roundtrip, b64 stores), B=V^T fragments (global pre-transposed).
// Output: lane holds O[q = lk*4+j][d = n*16+lr].

__global__ __launch_bounds__(256)
void attn_kernel(const ushort_t* __restrict__ qkv, const ushort_t* __restrict__ VtG,
                 const int* __restrict__ mask, ushort_t* __restrict__ att){
  const int qb = blockIdx.x, h = blockIdx.y, z = blockIdx.z;
  const int l = z >> 1, b = z & 1;
  const int* mrow = mask + b * 2048;
  const size_t base = ((size_t)(l * 4096 + b * 2048)) * 1536;
  const ushort_t* Qb = qkv + base + h * 64;
  const ushort_t* Kb = qkv + base + 512 + h * 64;
  const ushort_t* Vt = VtG + ((size_t)(z * 8 + h) * 64) * 2048;   // [64 d][2048 k]

  __shared__ ushort_t Ks[64 * 64];      // XOR-swizzled content (pre-swizzled global source)
  __shared__ ushort_t Vs[64 * 64];      // V^T tile, same swizzle
  __shared__ ushort_t Pl[4][16 * 72];   // per-wave P[q=16][k=64], stride 72

  const int tid = threadIdx.x, wid = tid >> 6, lane = tid & 63;
  const int lr = lane & 15, lk = lane >> 4;
  const int qrow = qb * 64 + wid * 16 + lr;

  // B-frag content for swapped QK: lane holds Q[q = wid*16+lr][d = lk*8..+8]
  const ushort_t* qp = Qb + (size_t)qrow * 1536 + lk * 8;
  const bf16x8 q0 = *(const bf16x8*)qp;
  const bf16x8 q1 = *(const bf16x8*)(qp + 32);

  f32x4 o[4] = {};
  float mrun = -3e38f, lrun = 0.f;

  for (int kt = 0; kt < 32; ++kt){
    const int k0 = kt * 64;
    // stage K tile [64 k][64 d] and V^T tile [64 d][64 k], sources pre-swizzled
    #pragma unroll
    for (int i = 0; i < 2; ++i){
      const int chunk = i * 256 + wid * 64 + lane;
      const int row = chunk >> 3, cc = (chunk & 7) ^ (row & 7);
      gload_lds16(Kb + (size_t)(k0 + row) * 1536 + cc * 8, &Ks[(i * 256 + wid * 64) * 8]);
      gload_lds16(Vt + (size_t)row * 2048 + (k0 + cc * 8), &Vs[(i * 256 + wid * 64) * 8]);
    }
    __syncthreads();

    // mask bits for this key tile
    const int mv = mrow[k0 + lane];
    const unsigned long long mbits = __ballot(mv != 0);

    // scores S^T: 4 hh blocks of 16 k-rows
    float sc[4][4];
    float smax = -3e38f;
    #pragma unroll
    for (int hh = 0; hh < 4; ++hh){
      const int sw = lr & 7;
      bf16x8 kf0 = *(const bf16x8*)&Ks[(hh * 16 + lr) * 64 + ((0 + lk) ^ sw) * 8];
      bf16x8 kf1 = *(const bf16x8*)&Ks[(hh * 16 + lr) * 64 + ((4 + lk) ^ sw) * 8];
      f32x4 t = {0.f, 0.f, 0.f, 0.f};
      t = __builtin_amdgcn_mfma_f32_16x16x32_bf16(kf0, q0, t, 0, 0, 0);
      t = __builtin_amdgcn_mfma_f32_16x16x32_bf16(kf1, q1, t, 0, 0, 0);
      const unsigned mh = (unsigned)(mbits >> (hh * 16)) & 0xffffu;
      #pragma unroll
      for (int j = 0; j < 4; ++j){
        const bool live = (mh >> (lk * 4 + j)) & 1u;
        const float v = live ? t[j] * 0.125f : -1e9f;
        sc[hh][j] = v;
        smax = fmaxf(smax, v);
      }
    }

    // online softmax: reduce across lk groups (same q = lr)
    smax = fmaxf(smax, __shfl_xor(smax, 16));
    smax = fmaxf(smax, __shfl_xor(smax, 32));
    const float mn = fmaxf(mrun, smax);
    const float scale = __expf(mrun - mn);
    mrun = mn;
    float psum = 0.f;
    short4v pk[4];
    #pragma unroll
    for (int hh = 0; hh < 4; ++hh)
      #pragma unroll
      for (int j = 0; j < 4; ++j){
        const float p = __expf(sc[hh][j] - mn);
        psum += p;
        pk[hh][j] = (short)f2bf(p);
      }
    psum += __shfl_xor(psum, 16);
    psum += __shfl_xor(psum, 32);
    lrun = lrun * scale + psum;

    // rescale O: o[n][j] belongs to q = lk*4+j; fetch that q's scale from lane lk*4+j
    float scj[4];
    #pragma unroll
    for (int j = 0; j < 4; ++j) scj[j] = __shfl(scale, lk * 4 + j);
    #pragma unroll
    for (int n = 0; n < 4; ++n)
      #pragma unroll
      for (int j = 0; j < 4; ++j)
        o[n][j] *= scj[j];

    // P -> per-wave LDS [q][k]: 4 aligned b64 stores (k = hh*16 + lk*4 .. +3)
    ushort_t* pw = &Pl[wid][0];
    #pragma unroll
    for (int hh = 0; hh < 4; ++hh)
      *(short4v*)&pw[lr * 72 + hh * 16 + lk * 4] = pk[hh];
    asm volatile("s_waitcnt lgkmcnt(0)" ::: "memory");
    __builtin_amdgcn_sched_barrier(0);
    const bf16x8 pf0 = *(const bf16x8*)&pw[lr * 72 + lk * 8];
    const bf16x8 pf1 = *(const bf16x8*)&pw[lr * 72 + 32 + lk * 8];

    #pragma unroll
    for (int n = 0; n < 4; ++n){
      const int sw = lr & 7;
      bf16x8 v0 = *(const bf16x8*)&Vs[(n * 16 + lr) * 64 + ((0 + lk) ^ sw) * 8];
      bf16x8 v1 = *(const bf16x8*)&Vs[(n * 16 + lr) * 64 + ((4 + lk) ^ sw) * 8];
      o[n] = __builtin_amdgcn_mfma_f32_16x16x32_bf16(pf0, v0, o[n], 0, 0, 0);
      o[n] = __builtin_amdgcn_mfma_f32_16x16x32_bf16(pf1, v1, o[n], 0, 0, 0);
    }
    __syncthreads();
  }

  // epilogue: lane holds O[q = lk*4+j][d = n*16+lr]; lrun lives at lane lk*4+j
  float invj[4];
  #pragma unroll
  for (int j = 0; j < 4; ++j) invj[j] = 1.0f / __shfl(lrun, lk * 4 + j);
  const size_t arow0 = (size_t)(b * 2048 + qb * 64 + wid * 16);
  #pragma unroll
  for (int n = 0; n < 4; ++n)
    #pragma unroll
    for (int j = 0; j < 4; ++j)
      att[(arow0 + lk * 4 + j) * 1536 + l * 512 + h * 64 + n * 16 + lr] = f2bf(o[n][j] * invj[j]);
}

// ---------------- launch ----------------

extern "C" void kernel_launch(void* const* d_in, const int* in_sizes, int n_in,
                              void* d_out, int out_size, void* d_ws, size_t ws_size,
                              hipStream_t stream){
  const float* x    = (const float*)d_in[0];
  const int*   mask = (const int*)d_in[1];
  const float* Wp   = (const float*)d_in[2];
  const float* bp   = (const float*)d_in[3];
  const float* gamma= (const float*)d_in[4];
  const float* beta = (const float*)d_in[5];
  const float* Wq   = (const float*)d_in[6];
  const float* bq   = (const float*)d_in[7];
  const float* Wk   = (const float*)d_in[8];
  const float* bk   = (const float*)d_in[9];
  const float* Wv   = (const float*)d_in[10];
  const float* bv   = (const float*)d_in[11];
  const float* Wo   = (const float*)d_in[12];
  const float* bo   = (const float*)d_in[13];
  const float* Wout = (const float*)d_in[14];
  const float* bout = (const float*)d_in[15];

  char* ws = (char*)d_ws;
  size_t off = 0;
  auto alloc = [&](size_t bytes){ void* p = ws + off; off += (bytes + 255) & ~(size_t)255; return p; };
  ushort_t* xb    = (ushort_t*)alloc(4096ull * 512 * 2);
  ushort_t* WpT   = (ushort_t*)alloc(1536ull * 512 * 2);
  ushort_t* WqkvT = (ushort_t*)alloc(3ull * 1536 * 512 * 2);
  ushort_t* WoT   = (ushort_t*)alloc(3ull * 512 * 512 * 2);
  ushort_t* WoutT = (ushort_t*)alloc(512ull * 1536 * 2);
  float*    bqkv  = (float*)alloc(3ull * 1536 * 4);
  float*    xl    = (float*)alloc(4096ull * 1536 * 4);
  ushort_t* xn    = (ushort_t*)alloc(4096ull * 1536 * 2);
  ushort_t* qkv   = (ushort_t*)alloc(3ull * 4096 * 1536 * 2);
  ushort_t* lev   = (ushort_t*)alloc(4096ull * 1536 * 2);
  ushort_t* att   = (ushort_t*)xl;  // alias: xl dead after ln_kernel
  ushort_t* VtG   = (ushort_t*)xn;  // alias: xn dead after QKV GEMM (48*64*2048*2 = 12.58MB = sizeof xn)

  cast4_kernel<<<2048, 256, 0, stream>>>(x, xb, 524288);
  transpose_cast<<<dim3(16, 16, 3), 256, 0, stream>>>(Wp, WpT, 512, 512, 262144, 262144);
  transpose_cast<<<dim3(16, 16, 3), 256, 0, stream>>>(Wq, WqkvT + 0,      512, 512, 262144, 786432);
  transpose_cast<<<dim3(16, 16, 3), 256, 0, stream>>>(Wk, WqkvT + 262144, 512, 512, 262144, 786432);
  transpose_cast<<<dim3(16, 16, 3), 256, 0, stream>>>(Wv, WqkvT + 524288, 512, 512, 262144, 786432);
  transpose_cast<<<dim3(16, 16, 3), 256, 0, stream>>>(Wo, WoT, 512, 512, 262144, 262144);
  transpose_cast<<<dim3(16, 48, 1), 256, 0, stream>>>(Wout, WoutT, 1536, 512, 0, 0);
  build_bqkv<<<18, 256, 0, stream>>>(bq, bk, bv, bqkv);

  // xl = x @ Wp + bp   [4096,1536] fp32
  gemm_bt<0><<<dim3(12, 32, 1), 256, 0, stream>>>(xb, WpT, bp, xl,
      4096, 1536, 512, 512, 512, 1536, 0, 0, 0, 0);
  // LayerNorm -> xn bf16
  ln_kernel<<<3072, 256, 0, stream>>>(xl, xn, gamma, beta);
  // qkv[l] = xn[l] @ Wqkv[l] + bqkv[l]   bf16 [3][4096][1536]
  gemm_bt<1><<<dim3(12, 32, 3), 256, 0, stream>>>(xn, WqkvT, bqkv, qkv,
      4096, 1536, 512, 1536, 512, 1536, 512, 786432, 4096ll * 1536, 1536);
  // V^T global pre-transpose (xn is dead now; VtG aliases it)
  vtrans_kernel<<<dim3(32, 8, 6), 256, 0, stream>>>(qkv, VtG);
  // flash attention -> att bf16 [4096][1536]
  attn_kernel<<<dim3(32, 8, 6), 256, 0, stream>>>(qkv, VtG, mask, att);
  // lev[l] = att[l] @ Wo[l] + bo[l]   bf16 [4096][1536]
  gemm_bt<1><<<dim3(4, 32, 3), 256, 0, stream>>>(att, WoT, bo, lev,
      4096, 512, 512, 1536, 512, 1536, 512, 262144, 512, 512);
  // out = lev @ Wout + bout   fp32 [4096][512]
  gemm_bt<0><<<dim3(4, 32, 1), 256, 0, stream>>>(lev, WoutT, bout, (float*)d_out,
      4096, 512, 1536, 1536, 1536, 512, 0, 0, 0, 0);
}